// Round 16
// baseline (260.949 us; speedup 1.0000x reference)
//
#include <hip/hip_runtime.h>
#include <hip/hip_bf16.h>
#include <math.h>

#define BB 4
#define II 2048
#define AA 2048
#define EE 256
#define HH 4

#define LOG2E 1.4426950408889634f
#define SCL   (0.125f * LOG2E)

typedef __bf16 bf16_t;
typedef bf16_t bf16x8 __attribute__((ext_vector_type(8)));
typedef bf16_t bf16x4 __attribute__((ext_vector_type(4)));
typedef float  f32x4  __attribute__((ext_vector_type(4)));

static __device__ __forceinline__ f32x4 mfma16(bf16x8 a, bf16x8 b, f32x4 c) {
    return __builtin_amdgcn_mfma_f32_16x16x32_bf16(a, b, c, 0, 0, 0);
}

static __device__ __forceinline__ void glds16(const bf16_t* g, const bf16_t* l) {
    __builtin_amdgcn_global_load_lds(
        (const __attribute__((address_space(1))) void*)g,
        (__attribute__((address_space(3))) void*)l, 16, 0, 0);
}

// ---------------- fused pre-pass: Q/K/V projections + mass ----------------
static __device__ __forceinline__ void proj_body(
    const float* __restrict__ Aop, const float* __restrict__ Bop,
    bf16_t* __restrict__ Cout, int m0, int n0, int TRANS, float cscale,
    bf16_t (*sA)[72], bf16_t (*sB)[72])
{
    const int t = threadIdx.x;
    const int w = t >> 6, l = t & 63, g = l >> 4, q = l & 15;
    const int wm = w >> 1, wn = w & 1;
    const int r = t >> 2, s = t & 3;

    f32x4 acc[2][2] = {};

    for (int kt = 0; kt < 4; ++kt) {
        {
            const float* ga = Aop + (size_t)(m0 + r) * EE + kt * 64 + s * 16;
            float tmp[16];
            *(f32x4*)&tmp[0]  = *(const f32x4*)(ga + 0);
            *(f32x4*)&tmp[4]  = *(const f32x4*)(ga + 4);
            *(f32x4*)&tmp[8]  = *(const f32x4*)(ga + 8);
            *(f32x4*)&tmp[12] = *(const f32x4*)(ga + 12);
            bf16x8 w0, w1;
            #pragma unroll
            for (int i = 0; i < 8; ++i) { w0[i] = (bf16_t)tmp[i]; w1[i] = (bf16_t)tmp[8 + i]; }
            *(bf16x8*)&sA[r][s * 16]     = w0;
            *(bf16x8*)&sA[r][s * 16 + 8] = w1;
        }
        {
            const float* gb = Bop + (size_t)(n0 + r) * EE + kt * 64 + s * 16;
            float tmp[16];
            *(f32x4*)&tmp[0]  = *(const f32x4*)(gb + 0);
            *(f32x4*)&tmp[4]  = *(const f32x4*)(gb + 4);
            *(f32x4*)&tmp[8]  = *(const f32x4*)(gb + 8);
            *(f32x4*)&tmp[12] = *(const f32x4*)(gb + 12);
            bf16x8 w0, w1;
            #pragma unroll
            for (int i = 0; i < 8; ++i) { w0[i] = (bf16_t)tmp[i]; w1[i] = (bf16_t)tmp[8 + i]; }
            *(bf16x8*)&sB[r][s * 16]     = w0;
            *(bf16x8*)&sB[r][s * 16 + 8] = w1;
        }
        __syncthreads();
        #pragma unroll
        for (int ks = 0; ks < 2; ++ks) {
            bf16x8 aA[2], aB[2];
            #pragma unroll
            for (int f = 0; f < 2; ++f) {
                aA[f] = *(const bf16x8*)&sA[wm * 32 + f * 16 + q][ks * 32 + g * 8];
                aB[f] = *(const bf16x8*)&sB[wn * 32 + f * 16 + q][ks * 32 + g * 8];
            }
            #pragma unroll
            for (int fm = 0; fm < 2; ++fm)
            #pragma unroll
            for (int fn = 0; fn < 2; ++fn)
                acc[fm][fn] = mfma16(aA[fm], aB[fn], acc[fm][fn]);
        }
        __syncthreads();
    }
    #pragma unroll
    for (int fm = 0; fm < 2; ++fm)
    #pragma unroll
    for (int fn = 0; fn < 2; ++fn)
    #pragma unroll
    for (int j = 0; j < 4; ++j) {
        const int m = m0 + wm * 32 + fm * 16 + g * 4 + j;
        const int n = n0 + wn * 32 + fn * 16 + q;
        const bf16_t v = (bf16_t)(acc[fm][fn][j] * cscale);
        if (TRANS == 0) {
            Cout[(size_t)m * EE + n] = v;
        } else {
            const int bb = n >> 11, a = n & (AA - 1);
            const int a6 = a & 63;
            const int p6 = (a6 & 32) | ((a6 & 12) << 1) | ((a6 & 16) >> 2) | (a6 & 3);
            Cout[(size_t)bb * (AA * EE) + (size_t)(a >> 6) * (EE * 64) + m * 64 + p6] = v;
        }
    }
}

__global__ __launch_bounds__(256) void fused_pre(
    const float* __restrict__ query, const float* __restrict__ key,
    const float* __restrict__ value, const float* __restrict__ in_w,
    const float* __restrict__ mass_w,
    bf16_t* __restrict__ Qp, bf16_t* __restrict__ Kp, bf16_t* __restrict__ Vt,
    float* __restrict__ massT)
{
    __shared__ __align__(16) bf16_t sA[64][72];
    __shared__ __align__(16) bf16_t sB[64][72];
    const int z = blockIdx.z;
    if (z == 0) {
        proj_body(query, in_w, Qp, blockIdx.x * 64, blockIdx.y * 64, 0, SCL, sA, sB);
    } else if (z == 1) {
        proj_body(key, in_w + 65536, Kp, blockIdx.x * 64, blockIdx.y * 64, 0, 1.0f, sA, sB);
    } else if (z == 2) {
        proj_body(in_w + 131072, value, Vt, blockIdx.y * 64, blockIdx.x * 64, 1, 1.0f, sA, sB);
    } else {
        const int w = threadIdx.x >> 6, l = threadIdx.x & 63;
        const int p = blockIdx.y * 128 + blockIdx.x;      // 0..511
        const int row0 = p * 16 + w * 4;
        f32x4 mw[HH];
        #pragma unroll
        for (int hh = 0; hh < HH; ++hh)
            mw[hh] = *(const f32x4*)(mass_w + hh * EE + l * 4);
        #pragma unroll
        for (int rr = 0; rr < 4; ++rr) {
            const int row = row0 + rr;                     // b*AA + a
            f32x4 kv = *(const f32x4*)(key + (size_t)row * EE + l * 4);
            f32x4 sd;
            #pragma unroll
            for (int hh = 0; hh < HH; ++hh)
                sd[hh] = kv[0]*mw[hh][0] + kv[1]*mw[hh][1] + kv[2]*mw[hh][2] + kv[3]*mw[hh][3];
            #pragma unroll
            for (int off = 32; off >= 1; off >>= 1) {
                #pragma unroll
                for (int hh = 0; hh < HH; ++hh) sd[hh] += __shfl_xor(sd[hh], off, 64);
            }
            if (l == 0) {
                const int bb = row >> 11, a = row & (AA - 1);
                #pragma unroll
                for (int hh = 0; hh < HH; ++hh) {
                    float ax = fabsf(sd[hh]);
                    massT[((size_t)bb * HH + hh) * AA + a] =
                        (ax + log1pf(__expf(-2.0f * ax)) - 0.693147180559945f) * LOG2E;
                }
            }
        }
    }
}

// ---------------- fused flash attention, quarter-split partials ----------------
// Grid (128,4,4) x 256 thr = 4 waves; blockIdx.x = it*4 + qa.
// Block = 64 i-rows x head h x a-quarter qa (8 tiles of 64 a starting qa*512).
// Wave rg owns 16 i-rows. Double-buffered K/V LDS (32KB -> 5 blocks/CU,
// 20 waves resident, 5 independent 4-wave barrier groups; supply 32/CU).
// Static-max softmax (scores bounded) => partials combine by PURE SUM:
// block writes f32 O-partial and l-partial; out_gemm fuses the 4-way sum
// and the 1/l normalize into its A-staging. Mass prefetched global->reg.
__global__ __launch_bounds__(256, 5) void attn_kernel(
    const bf16_t* __restrict__ Qp, const bf16_t* __restrict__ Kp,
    const bf16_t* __restrict__ Vt, const float* __restrict__ massT,
    const float* __restrict__ dist, float* __restrict__ Opart,
    float* __restrict__ Lpart)
{
    __shared__ __align__(16) bf16_t sK[2][4096];   // [buf][64a x 64d] chunk^=(row&7)
    __shared__ __align__(16) bf16_t sV[2][4096];   // [buf][64d x 64a'] chunk^=(row&7)

    const int t = threadIdx.x;
    const int rg = t >> 6, l = t & 63, g = l >> 4, q = l & 15;
    const int it = blockIdx.x >> 2, qa = blockIdx.x & 3;
    const int h = blockIdx.y, b = blockIdx.z;
    const int i0 = it * 64;
    const int a0 = qa * 512;

    // Q fragments (pre-scaled by SCL at projection)
    bf16x8 qf[2];
    #pragma unroll
    for (int ks = 0; ks < 2; ++ks)
        qf[ks] = *(const bf16x8*)(Qp + (size_t)(b * II + i0 + rg * 16 + q) * EE
                                     + h * 64 + ks * 32 + g * 8);

    // staging geometry: wave rg writes rows [rg*16, rg*16+16), lane covers (row, chunk)
    const int u0 = rg * 2;
    const int drow0 = u0 * 8 + (l >> 3);
    const int cs = (l & 7) ^ (drow0 & 7);   // constant pre-swizzled source chunk

    const bf16_t* pkg = Kp + ((size_t)b * AA + a0 + drow0) * EE + h * 64 + cs * 8;
    const bf16_t* pvg = Vt + (size_t)b * (AA * EE) + (size_t)(a0 >> 6) * (EE * 64)
                           + (size_t)(h * 64 + drow0) * 64 + cs * 8;
    const float*  pdg = dist + ((size_t)b * II + i0 + rg * 16 + q) * AA + a0 + g * 4;
    const float*  pmg = massT + ((size_t)b * HH + h) * AA + a0 + g * 4;

    auto stage = [&](int kb) {
        #pragma unroll
        for (int u = 0; u < 2; ++u) {
            glds16(pkg + u * (8 * EE), &sK[kb][(u0 + u) * 512]);
            glds16(pvg + u * (8 * 64), &sV[kb][(u0 + u) * 512]);
        }
    };

    // dist + mass double-sets (indices compile-time after unroll 2)
    f32x4 rd[2][4];
    f32x4 rm[2][4];

    stage(0);
    pkg += 64 * EE; pvg += EE * 64;
    #pragma unroll
    for (int fa = 0; fa < 4; ++fa) {
        rd[0][fa] = *(const f32x4*)(pdg + fa * 16);
        rm[0][fa] = *(const f32x4*)(pmg + fa * 16);
    }
    pdg += 64; pmg += 64;
    __syncthreads();

    f32x4 oacc[4] = {};
    f32x4 lacc = {};
    bf16x8 vone;
    #pragma unroll
    for (int j = 0; j < 8; ++j) vone[j] = (bf16_t)1.0f;

    #pragma unroll 2
    for (int k = 0; k < 8; ++k) {
        const int kb = k & 1;
        if (k < 7) {
            stage(kb ^ 1);
            pkg += 64 * EE; pvg += EE * 64;
            #pragma unroll
            for (int fa = 0; fa < 4; ++fa) {
                rd[kb ^ 1][fa] = *(const f32x4*)(pdg + fa * 16);
                rm[kb ^ 1][fa] = *(const f32x4*)(pmg + fa * 16);
            }
            pdg += 64; pmg += 64;
        }

        // ---- QK^T: S^T[a = fa*16+4g+j][i = q] ----
        f32x4 st[4] = {};
        __builtin_amdgcn_s_setprio(1);
        #pragma unroll
        for (int fa = 0; fa < 4; ++fa) {
            const int row = fa * 16 + q;
            #pragma unroll
            for (int ks = 0; ks < 2; ++ks) {
                bf16x8 ak = *(const bf16x8*)&sK[kb][row * 64 + (((ks * 4 + g) ^ (row & 7)) * 8)];
                st[fa] = mfma16(ak, qf[ks], st[fa]);
            }
        }
        __builtin_amdgcn_s_setprio(0);

        // ---- P = exp2(qk*scl - mass*dist)  (static max: scores bounded) ----
        #pragma unroll
        for (int fa = 0; fa < 4; ++fa) {
            #pragma unroll
            for (int j = 0; j < 4; ++j)
                st[fa][j] = exp2f(fmaf(-rm[kb][fa][j], rd[kb][fa][j], st[fa][j]));
        }

        // ---- pack P: slot (g,j) -> a = ka*32 + 16*(j>>2) + 4g + (j&3) ----
        bf16x8 pa[2];
        #pragma unroll
        for (int ka = 0; ka < 2; ++ka)
        #pragma unroll
        for (int j = 0; j < 8; ++j)
            pa[ka][j] = (bf16_t)st[2 * ka + (j >> 2)][j & 3];

        // ---- PV + ones-column denominator ----
        __builtin_amdgcn_s_setprio(1);
        #pragma unroll
        for (int ka = 0; ka < 2; ++ka) {
            #pragma unroll
            for (int fd = 0; fd < 4; ++fd) {
                const int row = fd * 16 + q;
                bf16x8 bv = *(const bf16x8*)&sV[kb][row * 64 + (((ka * 4 + g) ^ (row & 7)) * 8)];
                oacc[fd] = mfma16(pa[ka], bv, oacc[fd]);
            }
            lacc = mfma16(pa[ka], vone, lacc);
        }
        __builtin_amdgcn_s_setprio(0);

        __syncthreads();
    }

    // ---- write f32 partials (combine happens in out_gemm) ----
    float* Oq = Opart + (size_t)qa * ((size_t)BB * II * EE);
    #pragma unroll
    for (int fd = 0; fd < 4; ++fd)
    #pragma unroll
    for (int j = 0; j < 4; ++j)
        Oq[(size_t)(b * II + i0 + rg * 16 + g * 4 + j) * EE + h * 64 + fd * 16 + q]
            = oacc[fd][j];
    if (q == 0) {
        float* Lq = Lpart + (size_t)qa * (BB * HH * II);
        #pragma unroll
        for (int j = 0; j < 4; ++j)
            Lq[((size_t)b * HH + h) * II + i0 + rg * 16 + g * 4 + j] = lacc[j];
    }
}

// out[m][n] = sum_k A[m][k]*W[n][k], A = (sum_q Opart)*1/(sum_q Lpart), fused here.
__global__ __launch_bounds__(256) void out_gemm(
    const float* __restrict__ Opart, const float* __restrict__ Lpart,
    const float* __restrict__ Bop, float* __restrict__ Cout)
{
    __shared__ __align__(16) bf16_t sA[64][72];
    __shared__ __align__(16) bf16_t sB[64][72];
    const int t = threadIdx.x;
    const int w = t >> 6, l = t & 63, g = l >> 4, q = l & 15;
    const int wm = w >> 1, wn = w & 1;
    const int m0 = blockIdx.x * 64, n0 = blockIdx.y * 64;
    const int r = t >> 2, s = t & 3;

    const size_t OQ = (size_t)BB * II * EE;     // quarter stride (floats)
    const size_t LQ = (size_t)BB * HH * II;

    f32x4 acc[2][2] = {};

    for (int kt = 0; kt < 4; ++kt) {
        { // ---- A-stage: 4-quarter sum + normalize + bf16 ----
            const int m = m0 + r;
            const size_t lidx = ((size_t)(m >> 11) * HH + kt) * II + (m & (II - 1));
            const float lsum = Lpart[lidx] + Lpart[LQ + lidx]
                             + Lpart[2 * LQ + lidx] + Lpart[3 * LQ + lidx];
            const float invl = 1.0f / lsum;
            const float* po = Opart + (size_t)m * EE + kt * 64 + s * 16;
            bf16x8 w0, w1;
            #pragma unroll
            for (int vv = 0; vv < 4; ++vv) {
                f32x4 a4 = *(const f32x4*)(po + vv * 4);
                a4 = a4 + *(const f32x4*)(po + OQ + vv * 4);
                a4 = a4 + *(const f32x4*)(po + 2 * OQ + vv * 4);
                a4 = a4 + *(const f32x4*)(po + 3 * OQ + vv * 4);
                #pragma unroll
                for (int j = 0; j < 4; ++j) {
                    const bf16_t v = (bf16_t)(a4[j] * invl);
                    if (vv < 2) w0[vv * 4 + j] = v;
                    else        w1[(vv - 2) * 4 + j] = v;
                }
            }
            *(bf16x8*)&sA[r][s * 16]     = w0;
            *(bf16x8*)&sA[r][s * 16 + 8] = w1;
        }
        { // ---- B-stage (f32 -> bf16) ----
            const float* gb = Bop + (size_t)(n0 + r) * EE + kt * 64 + s * 16;
            float tmp[16];
            *(f32x4*)&tmp[0]  = *(const f32x4*)(gb + 0);
            *(f32x4*)&tmp[4]  = *(const f32x4*)(gb + 4);
            *(f32x4*)&tmp[8]  = *(const f32x4*)(gb + 8);
            *(f32x4*)&tmp[12] = *(const f32x4*)(gb + 12);
            bf16x8 w0, w1;
            #pragma unroll
            for (int i = 0; i < 8; ++i) { w0[i] = (bf16_t)tmp[i]; w1[i] = (bf16_t)tmp[8 + i]; }
            *(bf16x8*)&sB[r][s * 16]     = w0;
            *(bf16x8*)&sB[r][s * 16 + 8] = w1;
        }
        __syncthreads();
        #pragma unroll
        for (int ks = 0; ks < 2; ++ks) {
            bf16x8 aA[2], aB[2];
            #pragma unroll
            for (int f = 0; f < 2; ++f) {
                aA[f] = *(const bf16x8*)&sA[wm * 32 + f * 16 + q][ks * 32 + g * 8];
                aB[f] = *(const bf16x8*)&sB[wn * 32 + f * 16 + q][ks * 32 + g * 8];
            }
            #pragma unroll
            for (int fm = 0; fm < 2; ++fm)
            #pragma unroll
            for (int fn = 0; fn < 2; ++fn)
                acc[fm][fn] = mfma16(aA[fm], aB[fn], acc[fm][fn]);
        }
        __syncthreads();
    }
    #pragma unroll
    for (int fm = 0; fm < 2; ++fm)
    #pragma unroll
    for (int fn = 0; fn < 2; ++fn)
    #pragma unroll
    for (int j = 0; j < 4; ++j) {
        const int m = m0 + wm * 32 + fm * 16 + g * 4 + j;
        const int n = n0 + wn * 32 + fn * 16 + q;
        Cout[(size_t)m * EE + n] = acc[fm][fn][j];
    }
}

extern "C" void kernel_launch(void* const* d_in, const int* in_sizes, int n_in,
                              void* d_out, int out_size, void* d_ws, size_t ws_size,
                              hipStream_t stream)
{
    const float* query  = (const float*)d_in[0];
    const float* key    = (const float*)d_in[1];
    const float* value  = (const float*)d_in[2];
    const float* dist   = (const float*)d_in[3];
    const float* in_w   = (const float*)d_in[4];
    const float* out_w  = (const float*)d_in[5];
    const float* mass_w = (const float*)d_in[6];
    float* out = (float*)d_out;

    char* ws = (char*)d_ws;
    bf16_t* Qp    = (bf16_t*)(ws);
    bf16_t* Kp    = (bf16_t*)(ws + 1 * 4194304);
    bf16_t* Vt    = (bf16_t*)(ws + 2 * 4194304);
    float*  massT = (float*) (ws + 3 * 4194304);
    float*  Opart = (float*) (ws + 4 * 4194304);          // 4 x 8MB = 32MB
    float*  Lpart = (float*) (ws + 12 * 4194304);         // 4 x 128KB

    fused_pre<<<dim3(128, 4, 4), dim3(256), 0, stream>>>(
        query, key, value, in_w, mass_w, Qp, Kp, Vt, massT);
    attn_kernel<<<dim3(128, 4, 4), dim3(256), 0, stream>>>(
        Qp, Kp, Vt, massT, dist, Opart, Lpart);
    out_gemm<<<dim3(128, 4), dim3(256), 0, stream>>>(Opart, Lpart, out_w, out);
}

// Round 17
// 100.664 us; speedup vs baseline: 2.5923x; 2.5923x over previous
//
#include <hip/hip_runtime.h>
#include <hip/hip_bf16.h>
#include <math.h>

#define BB 4
#define II 2048
#define AA 2048
#define EE 256
#define HH 4

#define LOG2E 1.4426950408889634f
#define SCL   (0.125f * LOG2E)

typedef __bf16 bf16_t;
typedef bf16_t bf16x8 __attribute__((ext_vector_type(8)));
typedef bf16_t bf16x4 __attribute__((ext_vector_type(4)));
typedef float  f32x4  __attribute__((ext_vector_type(4)));

static __device__ __forceinline__ f32x4 mfma16(bf16x8 a, bf16x8 b, f32x4 c) {
    return __builtin_amdgcn_mfma_f32_16x16x32_bf16(a, b, c, 0, 0, 0);
}

static __device__ __forceinline__ void glds16(const bf16_t* g, const bf16_t* l) {
    __builtin_amdgcn_global_load_lds(
        (const __attribute__((address_space(1))) void*)g,
        (__attribute__((address_space(3))) void*)l, 16, 0, 0);
}

// ---------------- fused pre-pass: Q/K/V projections + mass ----------------
static __device__ __forceinline__ void proj_body(
    const float* __restrict__ Aop, const float* __restrict__ Bop,
    bf16_t* __restrict__ Cout, int m0, int n0, int TRANS, float cscale,
    bf16_t (*sA)[72], bf16_t (*sB)[72])
{
    const int t = threadIdx.x;
    const int w = t >> 6, l = t & 63, g = l >> 4, q = l & 15;
    const int wm = w >> 1, wn = w & 1;
    const int r = t >> 2, s = t & 3;

    f32x4 acc[2][2] = {};

    for (int kt = 0; kt < 4; ++kt) {
        {
            const float* ga = Aop + (size_t)(m0 + r) * EE + kt * 64 + s * 16;
            float tmp[16];
            *(f32x4*)&tmp[0]  = *(const f32x4*)(ga + 0);
            *(f32x4*)&tmp[4]  = *(const f32x4*)(ga + 4);
            *(f32x4*)&tmp[8]  = *(const f32x4*)(ga + 8);
            *(f32x4*)&tmp[12] = *(const f32x4*)(ga + 12);
            bf16x8 w0, w1;
            #pragma unroll
            for (int i = 0; i < 8; ++i) { w0[i] = (bf16_t)tmp[i]; w1[i] = (bf16_t)tmp[8 + i]; }
            *(bf16x8*)&sA[r][s * 16]     = w0;
            *(bf16x8*)&sA[r][s * 16 + 8] = w1;
        }
        {
            const float* gb = Bop + (size_t)(n0 + r) * EE + kt * 64 + s * 16;
            float tmp[16];
            *(f32x4*)&tmp[0]  = *(const f32x4*)(gb + 0);
            *(f32x4*)&tmp[4]  = *(const f32x4*)(gb + 4);
            *(f32x4*)&tmp[8]  = *(const f32x4*)(gb + 8);
            *(f32x4*)&tmp[12] = *(const f32x4*)(gb + 12);
            bf16x8 w0, w1;
            #pragma unroll
            for (int i = 0; i < 8; ++i) { w0[i] = (bf16_t)tmp[i]; w1[i] = (bf16_t)tmp[8 + i]; }
            *(bf16x8*)&sB[r][s * 16]     = w0;
            *(bf16x8*)&sB[r][s * 16 + 8] = w1;
        }
        __syncthreads();
        #pragma unroll
        for (int ks = 0; ks < 2; ++ks) {
            bf16x8 aA[2], aB[2];
            #pragma unroll
            for (int f = 0; f < 2; ++f) {
                aA[f] = *(const bf16x8*)&sA[wm * 32 + f * 16 + q][ks * 32 + g * 8];
                aB[f] = *(const bf16x8*)&sB[wn * 32 + f * 16 + q][ks * 32 + g * 8];
            }
            #pragma unroll
            for (int fm = 0; fm < 2; ++fm)
            #pragma unroll
            for (int fn = 0; fn < 2; ++fn)
                acc[fm][fn] = mfma16(aA[fm], aB[fn], acc[fm][fn]);
        }
        __syncthreads();
    }
    #pragma unroll
    for (int fm = 0; fm < 2; ++fm)
    #pragma unroll
    for (int fn = 0; fn < 2; ++fn)
    #pragma unroll
    for (int j = 0; j < 4; ++j) {
        const int m = m0 + wm * 32 + fm * 16 + g * 4 + j;
        const int n = n0 + wn * 32 + fn * 16 + q;
        const bf16_t v = (bf16_t)(acc[fm][fn][j] * cscale);
        if (TRANS == 0) {
            Cout[(size_t)m * EE + n] = v;
        } else {
            const int bb = n >> 11, a = n & (AA - 1);
            const int a6 = a & 63;
            const int p6 = (a6 & 32) | ((a6 & 12) << 1) | ((a6 & 16) >> 2) | (a6 & 3);
            Cout[(size_t)bb * (AA * EE) + (size_t)(a >> 6) * (EE * 64) + m * 64 + p6] = v;
        }
    }
}

__global__ __launch_bounds__(256) void fused_pre(
    const float* __restrict__ query, const float* __restrict__ key,
    const float* __restrict__ value, const float* __restrict__ in_w,
    const float* __restrict__ mass_w,
    bf16_t* __restrict__ Qp, bf16_t* __restrict__ Kp, bf16_t* __restrict__ Vt,
    float* __restrict__ massT)
{
    __shared__ __align__(16) bf16_t sA[64][72];
    __shared__ __align__(16) bf16_t sB[64][72];
    const int z = blockIdx.z;
    if (z == 0) {
        proj_body(query, in_w, Qp, blockIdx.x * 64, blockIdx.y * 64, 0, SCL, sA, sB);
    } else if (z == 1) {
        proj_body(key, in_w + 65536, Kp, blockIdx.x * 64, blockIdx.y * 64, 0, 1.0f, sA, sB);
    } else if (z == 2) {
        proj_body(in_w + 131072, value, Vt, blockIdx.y * 64, blockIdx.x * 64, 1, 1.0f, sA, sB);
    } else {
        const int w = threadIdx.x >> 6, l = threadIdx.x & 63;
        const int p = blockIdx.y * 128 + blockIdx.x;      // 0..511
        const int row0 = p * 16 + w * 4;
        f32x4 mw[HH];
        #pragma unroll
        for (int hh = 0; hh < HH; ++hh)
            mw[hh] = *(const f32x4*)(mass_w + hh * EE + l * 4);
        #pragma unroll
        for (int rr = 0; rr < 4; ++rr) {
            const int row = row0 + rr;                     // b*AA + a
            f32x4 kv = *(const f32x4*)(key + (size_t)row * EE + l * 4);
            f32x4 sd;
            #pragma unroll
            for (int hh = 0; hh < HH; ++hh)
                sd[hh] = kv[0]*mw[hh][0] + kv[1]*mw[hh][1] + kv[2]*mw[hh][2] + kv[3]*mw[hh][3];
            #pragma unroll
            for (int off = 32; off >= 1; off >>= 1) {
                #pragma unroll
                for (int hh = 0; hh < HH; ++hh) sd[hh] += __shfl_xor(sd[hh], off, 64);
            }
            if (l == 0) {
                const int bb = row >> 11, a = row & (AA - 1);
                #pragma unroll
                for (int hh = 0; hh < HH; ++hh) {
                    float ax = fabsf(sd[hh]);
                    massT[((size_t)bb * HH + hh) * AA + a] =
                        (ax + log1pf(__expf(-2.0f * ax)) - 0.693147180559945f) * LOG2E;
                }
            }
        }
    }
}

// ---------------- fused flash attention, quarter-split partials ----------------
// Grid (128,4,4) x 256 thr = 4 waves; blockIdx.x = it*4 + qa.
// Block = 64 i-rows x head h x a-quarter qa (8 tiles of 64 a starting qa*512).
// Wave rg owns 16 i-rows. Double-buffered K/V LDS (32KB allows 5 blocks/CU;
// supply 32 waves/CU). Static-max softmax => partials combine by PURE SUM:
// block writes f32 O-partial and l-partial; out_gemm fuses the 4-way sum
// and the 1/l normalize into its A-staging. Mass prefetched global->reg.
// launch_bounds(256,2): session data shows min-occupancy args >=4 force the
// allocator below the body's ~60-VGPR need and spill (r16: 48 VGPR, 440MB
// scratch writes); <=3 allocates body-need without spill.
__global__ __launch_bounds__(256, 2) void attn_kernel(
    const bf16_t* __restrict__ Qp, const bf16_t* __restrict__ Kp,
    const bf16_t* __restrict__ Vt, const float* __restrict__ massT,
    const float* __restrict__ dist, float* __restrict__ Opart,
    float* __restrict__ Lpart)
{
    __shared__ __align__(16) bf16_t sK[2][4096];   // [buf][64a x 64d] chunk^=(row&7)
    __shared__ __align__(16) bf16_t sV[2][4096];   // [buf][64d x 64a'] chunk^=(row&7)

    const int t = threadIdx.x;
    const int rg = t >> 6, l = t & 63, g = l >> 4, q = l & 15;
    const int it = blockIdx.x >> 2, qa = blockIdx.x & 3;
    const int h = blockIdx.y, b = blockIdx.z;
    const int i0 = it * 64;
    const int a0 = qa * 512;

    // Q fragments (pre-scaled by SCL at projection)
    bf16x8 qf[2];
    #pragma unroll
    for (int ks = 0; ks < 2; ++ks)
        qf[ks] = *(const bf16x8*)(Qp + (size_t)(b * II + i0 + rg * 16 + q) * EE
                                     + h * 64 + ks * 32 + g * 8);

    // staging geometry: wave rg writes rows [rg*16, rg*16+16), lane covers (row, chunk)
    const int u0 = rg * 2;
    const int drow0 = u0 * 8 + (l >> 3);
    const int cs = (l & 7) ^ (drow0 & 7);   // constant pre-swizzled source chunk

    const bf16_t* pkg = Kp + ((size_t)b * AA + a0 + drow0) * EE + h * 64 + cs * 8;
    const bf16_t* pvg = Vt + (size_t)b * (AA * EE) + (size_t)(a0 >> 6) * (EE * 64)
                           + (size_t)(h * 64 + drow0) * 64 + cs * 8;
    const float*  pdg = dist + ((size_t)b * II + i0 + rg * 16 + q) * AA + a0 + g * 4;
    const float*  pmg = massT + ((size_t)b * HH + h) * AA + a0 + g * 4;

    auto stage = [&](int kb) {
        #pragma unroll
        for (int u = 0; u < 2; ++u) {
            glds16(pkg + u * (8 * EE), &sK[kb][(u0 + u) * 512]);
            glds16(pvg + u * (8 * 64), &sV[kb][(u0 + u) * 512]);
        }
    };

    // dist + mass double-sets (indices compile-time after unroll 2)
    f32x4 rd[2][4];
    f32x4 rm[2][4];

    stage(0);
    pkg += 64 * EE; pvg += EE * 64;
    #pragma unroll
    for (int fa = 0; fa < 4; ++fa) {
        rd[0][fa] = *(const f32x4*)(pdg + fa * 16);
        rm[0][fa] = *(const f32x4*)(pmg + fa * 16);
    }
    pdg += 64; pmg += 64;
    __syncthreads();

    f32x4 oacc[4] = {};
    f32x4 lacc = {};
    bf16x8 vone;
    #pragma unroll
    for (int j = 0; j < 8; ++j) vone[j] = (bf16_t)1.0f;

    #pragma unroll 2
    for (int k = 0; k < 8; ++k) {
        const int kb = k & 1;
        if (k < 7) {
            stage(kb ^ 1);
            pkg += 64 * EE; pvg += EE * 64;
            #pragma unroll
            for (int fa = 0; fa < 4; ++fa) {
                rd[kb ^ 1][fa] = *(const f32x4*)(pdg + fa * 16);
                rm[kb ^ 1][fa] = *(const f32x4*)(pmg + fa * 16);
            }
            pdg += 64; pmg += 64;
        }

        // ---- QK^T: S^T[a = fa*16+4g+j][i = q] ----
        f32x4 st[4] = {};
        __builtin_amdgcn_s_setprio(1);
        #pragma unroll
        for (int fa = 0; fa < 4; ++fa) {
            const int row = fa * 16 + q;
            #pragma unroll
            for (int ks = 0; ks < 2; ++ks) {
                bf16x8 ak = *(const bf16x8*)&sK[kb][row * 64 + (((ks * 4 + g) ^ (row & 7)) * 8)];
                st[fa] = mfma16(ak, qf[ks], st[fa]);
            }
        }
        __builtin_amdgcn_s_setprio(0);

        // ---- P = exp2(qk*scl - mass*dist)  (static max: scores bounded) ----
        #pragma unroll
        for (int fa = 0; fa < 4; ++fa) {
            #pragma unroll
            for (int j = 0; j < 4; ++j)
                st[fa][j] = exp2f(fmaf(-rm[kb][fa][j], rd[kb][fa][j], st[fa][j]));
        }

        // ---- pack P: slot (g,j) -> a = ka*32 + 16*(j>>2) + 4g + (j&3) ----
        bf16x8 pa[2];
        #pragma unroll
        for (int ka = 0; ka < 2; ++ka)
        #pragma unroll
        for (int j = 0; j < 8; ++j)
            pa[ka][j] = (bf16_t)st[2 * ka + (j >> 2)][j & 3];

        // ---- PV + ones-column denominator ----
        __builtin_amdgcn_s_setprio(1);
        #pragma unroll
        for (int ka = 0; ka < 2; ++ka) {
            #pragma unroll
            for (int fd = 0; fd < 4; ++fd) {
                const int row = fd * 16 + q;
                bf16x8 bv = *(const bf16x8*)&sV[kb][row * 64 + (((ka * 4 + g) ^ (row & 7)) * 8)];
                oacc[fd] = mfma16(pa[ka], bv, oacc[fd]);
            }
            lacc = mfma16(pa[ka], vone, lacc);
        }
        __builtin_amdgcn_s_setprio(0);

        __syncthreads();
    }

    // ---- write f32 partials (combine happens in out_gemm) ----
    float* Oq = Opart + (size_t)qa * ((size_t)BB * II * EE);
    #pragma unroll
    for (int fd = 0; fd < 4; ++fd)
    #pragma unroll
    for (int j = 0; j < 4; ++j)
        Oq[(size_t)(b * II + i0 + rg * 16 + g * 4 + j) * EE + h * 64 + fd * 16 + q]
            = oacc[fd][j];
    if (q == 0) {
        float* Lq = Lpart + (size_t)qa * (BB * HH * II);
        #pragma unroll
        for (int j = 0; j < 4; ++j)
            Lq[((size_t)b * HH + h) * II + i0 + rg * 16 + g * 4 + j] = lacc[j];
    }
}

// out[m][n] = sum_k A[m][k]*W[n][k], A = (sum_q Opart)*1/(sum_q Lpart), fused here.
__global__ __launch_bounds__(256) void out_gemm(
    const float* __restrict__ Opart, const float* __restrict__ Lpart,
    const float* __restrict__ Bop, float* __restrict__ Cout)
{
    __shared__ __align__(16) bf16_t sA[64][72];
    __shared__ __align__(16) bf16_t sB[64][72];
    const int t = threadIdx.x;
    const int w = t >> 6, l = t & 63, g = l >> 4, q = l & 15;
    const int wm = w >> 1, wn = w & 1;
    const int m0 = blockIdx.x * 64, n0 = blockIdx.y * 64;
    const int r = t >> 2, s = t & 3;

    const size_t OQ = (size_t)BB * II * EE;     // quarter stride (floats)
    const size_t LQ = (size_t)BB * HH * II;

    f32x4 acc[2][2] = {};

    for (int kt = 0; kt < 4; ++kt) {
        { // ---- A-stage: 4-quarter sum + normalize + bf16 ----
            const int m = m0 + r;
            const size_t lidx = ((size_t)(m >> 11) * HH + kt) * II + (m & (II - 1));
            const float lsum = Lpart[lidx] + Lpart[LQ + lidx]
                             + Lpart[2 * LQ + lidx] + Lpart[3 * LQ + lidx];
            const float invl = 1.0f / lsum;
            const float* po = Opart + (size_t)m * EE + kt * 64 + s * 16;
            bf16x8 w0, w1;
            #pragma unroll
            for (int vv = 0; vv < 4; ++vv) {
                f32x4 a4 = *(const f32x4*)(po + vv * 4);
                a4 = a4 + *(const f32x4*)(po + OQ + vv * 4);
                a4 = a4 + *(const f32x4*)(po + 2 * OQ + vv * 4);
                a4 = a4 + *(const f32x4*)(po + 3 * OQ + vv * 4);
                #pragma unroll
                for (int j = 0; j < 4; ++j) {
                    const bf16_t v = (bf16_t)(a4[j] * invl);
                    if (vv < 2) w0[vv * 4 + j] = v;
                    else        w1[(vv - 2) * 4 + j] = v;
                }
            }
            *(bf16x8*)&sA[r][s * 16]     = w0;
            *(bf16x8*)&sA[r][s * 16 + 8] = w1;
        }
        { // ---- B-stage (f32 -> bf16) ----
            const float* gb = Bop + (size_t)(n0 + r) * EE + kt * 64 + s * 16;
            float tmp[16];
            *(f32x4*)&tmp[0]  = *(const f32x4*)(gb + 0);
            *(f32x4*)&tmp[4]  = *(const f32x4*)(gb + 4);
            *(f32x4*)&tmp[8]  = *(const f32x4*)(gb + 8);
            *(f32x4*)&tmp[12] = *(const f32x4*)(gb + 12);
            bf16x8 w0, w1;
            #pragma unroll
            for (int i = 0; i < 8; ++i) { w0[i] = (bf16_t)tmp[i]; w1[i] = (bf16_t)tmp[8 + i]; }
            *(bf16x8*)&sB[r][s * 16]     = w0;
            *(bf16x8*)&sB[r][s * 16 + 8] = w1;
        }
        __syncthreads();
        #pragma unroll
        for (int ks = 0; ks < 2; ++ks) {
            bf16x8 aA[2], aB[2];
            #pragma unroll
            for (int f = 0; f < 2; ++f) {
                aA[f] = *(const bf16x8*)&sA[wm * 32 + f * 16 + q][ks * 32 + g * 8];
                aB[f] = *(const bf16x8*)&sB[wn * 32 + f * 16 + q][ks * 32 + g * 8];
            }
            #pragma unroll
            for (int fm = 0; fm < 2; ++fm)
            #pragma unroll
            for (int fn = 0; fn < 2; ++fn)
                acc[fm][fn] = mfma16(aA[fm], aB[fn], acc[fm][fn]);
        }
        __syncthreads();
    }
    #pragma unroll
    for (int fm = 0; fm < 2; ++fm)
    #pragma unroll
    for (int fn = 0; fn < 2; ++fn)
    #pragma unroll
    for (int j = 0; j < 4; ++j) {
        const int m = m0 + wm * 32 + fm * 16 + g * 4 + j;
        const int n = n0 + wn * 32 + fn * 16 + q;
        Cout[(size_t)m * EE + n] = acc[fm][fn][j];
    }
}

extern "C" void kernel_launch(void* const* d_in, const int* in_sizes, int n_in,
                              void* d_out, int out_size, void* d_ws, size_t ws_size,
                              hipStream_t stream)
{
    const float* query  = (const float*)d_in[0];
    const float* key    = (const float*)d_in[1];
    const float* value  = (const float*)d_in[2];
    const float* dist   = (const float*)d_in[3];
    const float* in_w   = (const float*)d_in[4];
    const float* out_w  = (const float*)d_in[5];
    const float* mass_w = (const float*)d_in[6];
    float* out = (float*)d_out;

    char* ws = (char*)d_ws;
    bf16_t* Qp    = (bf16_t*)(ws);
    bf16_t* Kp    = (bf16_t*)(ws + 1 * 4194304);
    bf16_t* Vt    = (bf16_t*)(ws + 2 * 4194304);
    float*  massT = (float*) (ws + 3 * 4194304);
    float*  Opart = (float*) (ws + 4 * 4194304);          // 4 x 8MB = 32MB
    float*  Lpart = (float*) (ws + 12 * 4194304);         // 4 x 128KB

    fused_pre<<<dim3(128, 4, 4), dim3(256), 0, stream>>>(
        query, key, value, in_w, mass_w, Qp, Kp, Vt, massT);
    attn_kernel<<<dim3(128, 4, 4), dim3(256), 0, stream>>>(
        Qp, Kp, Vt, massT, dist, Opart, Lpart);
    out_gemm<<<dim3(128, 4), dim3(256), 0, stream>>>(Opart, Lpart, out_w, out);
}

// Round 18
// 80.562 us; speedup vs baseline: 3.2391x; 1.2495x over previous
//
#include <hip/hip_runtime.h>
#include <hip/hip_bf16.h>
#include <math.h>

#define BB 4
#define II 2048
#define AA 2048
#define EE 256
#define HH 4

#define LOG2E 1.4426950408889634f
#define SCL   (0.125f * LOG2E)

typedef __bf16 bf16_t;
typedef bf16_t bf16x8 __attribute__((ext_vector_type(8)));
typedef bf16_t bf16x4 __attribute__((ext_vector_type(4)));
typedef float  f32x4  __attribute__((ext_vector_type(4)));

static __device__ __forceinline__ f32x4 mfma16(bf16x8 a, bf16x8 b, f32x4 c) {
    return __builtin_amdgcn_mfma_f32_16x16x32_bf16(a, b, c, 0, 0, 0);
}

static __device__ __forceinline__ void glds16(const bf16_t* g, const bf16_t* l) {
    __builtin_amdgcn_global_load_lds(
        (const __attribute__((address_space(1))) void*)g,
        (__attribute__((address_space(3))) void*)l, 16, 0, 0);
}

// ---------------- fused pre-pass: Q/K/V projections + mass ----------------
static __device__ __forceinline__ void proj_body(
    const float* __restrict__ Aop, const float* __restrict__ Bop,
    bf16_t* __restrict__ Cout, int m0, int n0, int TRANS, float cscale,
    bf16_t (*sA)[72], bf16_t (*sB)[72])
{
    const int t = threadIdx.x;
    const int w = t >> 6, l = t & 63, g = l >> 4, q = l & 15;
    const int wm = w >> 1, wn = w & 1;
    const int r = t >> 2, s = t & 3;

    f32x4 acc[2][2] = {};

    for (int kt = 0; kt < 4; ++kt) {
        {
            const float* ga = Aop + (size_t)(m0 + r) * EE + kt * 64 + s * 16;
            float tmp[16];
            *(f32x4*)&tmp[0]  = *(const f32x4*)(ga + 0);
            *(f32x4*)&tmp[4]  = *(const f32x4*)(ga + 4);
            *(f32x4*)&tmp[8]  = *(const f32x4*)(ga + 8);
            *(f32x4*)&tmp[12] = *(const f32x4*)(ga + 12);
            bf16x8 w0, w1;
            #pragma unroll
            for (int i = 0; i < 8; ++i) { w0[i] = (bf16_t)tmp[i]; w1[i] = (bf16_t)tmp[8 + i]; }
            *(bf16x8*)&sA[r][s * 16]     = w0;
            *(bf16x8*)&sA[r][s * 16 + 8] = w1;
        }
        {
            const float* gb = Bop + (size_t)(n0 + r) * EE + kt * 64 + s * 16;
            float tmp[16];
            *(f32x4*)&tmp[0]  = *(const f32x4*)(gb + 0);
            *(f32x4*)&tmp[4]  = *(const f32x4*)(gb + 4);
            *(f32x4*)&tmp[8]  = *(const f32x4*)(gb + 8);
            *(f32x4*)&tmp[12] = *(const f32x4*)(gb + 12);
            bf16x8 w0, w1;
            #pragma unroll
            for (int i = 0; i < 8; ++i) { w0[i] = (bf16_t)tmp[i]; w1[i] = (bf16_t)tmp[8 + i]; }
            *(bf16x8*)&sB[r][s * 16]     = w0;
            *(bf16x8*)&sB[r][s * 16 + 8] = w1;
        }
        __syncthreads();
        #pragma unroll
        for (int ks = 0; ks < 2; ++ks) {
            bf16x8 aA[2], aB[2];
            #pragma unroll
            for (int f = 0; f < 2; ++f) {
                aA[f] = *(const bf16x8*)&sA[wm * 32 + f * 16 + q][ks * 32 + g * 8];
                aB[f] = *(const bf16x8*)&sB[wn * 32 + f * 16 + q][ks * 32 + g * 8];
            }
            #pragma unroll
            for (int fm = 0; fm < 2; ++fm)
            #pragma unroll
            for (int fn = 0; fn < 2; ++fn)
                acc[fm][fn] = mfma16(aA[fm], aB[fn], acc[fm][fn]);
        }
        __syncthreads();
    }
    #pragma unroll
    for (int fm = 0; fm < 2; ++fm)
    #pragma unroll
    for (int fn = 0; fn < 2; ++fn)
    #pragma unroll
    for (int j = 0; j < 4; ++j) {
        const int m = m0 + wm * 32 + fm * 16 + g * 4 + j;
        const int n = n0 + wn * 32 + fn * 16 + q;
        const bf16_t v = (bf16_t)(acc[fm][fn][j] * cscale);
        if (TRANS == 0) {
            Cout[(size_t)m * EE + n] = v;
        } else {
            const int bb = n >> 11, a = n & (AA - 1);
            const int a6 = a & 63;
            const int p6 = (a6 & 32) | ((a6 & 12) << 1) | ((a6 & 16) >> 2) | (a6 & 3);
            Cout[(size_t)bb * (AA * EE) + (size_t)(a >> 6) * (EE * 64) + m * 64 + p6] = v;
        }
    }
}

__global__ __launch_bounds__(256) void fused_pre(
    const float* __restrict__ query, const float* __restrict__ key,
    const float* __restrict__ value, const float* __restrict__ in_w,
    const float* __restrict__ mass_w,
    bf16_t* __restrict__ Qp, bf16_t* __restrict__ Kp, bf16_t* __restrict__ Vt,
    float* __restrict__ massT)
{
    __shared__ __align__(16) bf16_t sA[64][72];
    __shared__ __align__(16) bf16_t sB[64][72];
    const int z = blockIdx.z;
    if (z == 0) {
        proj_body(query, in_w, Qp, blockIdx.x * 64, blockIdx.y * 64, 0, SCL, sA, sB);
    } else if (z == 1) {
        proj_body(key, in_w + 65536, Kp, blockIdx.x * 64, blockIdx.y * 64, 0, 1.0f, sA, sB);
    } else if (z == 2) {
        proj_body(in_w + 131072, value, Vt, blockIdx.y * 64, blockIdx.x * 64, 1, 1.0f, sA, sB);
    } else {
        const int w = threadIdx.x >> 6, l = threadIdx.x & 63;
        const int p = blockIdx.y * 128 + blockIdx.x;      // 0..511
        const int row0 = p * 16 + w * 4;
        f32x4 mw[HH];
        #pragma unroll
        for (int hh = 0; hh < HH; ++hh)
            mw[hh] = *(const f32x4*)(mass_w + hh * EE + l * 4);
        #pragma unroll
        for (int rr = 0; rr < 4; ++rr) {
            const int row = row0 + rr;                     // b*AA + a
            f32x4 kv = *(const f32x4*)(key + (size_t)row * EE + l * 4);
            f32x4 sd;
            #pragma unroll
            for (int hh = 0; hh < HH; ++hh)
                sd[hh] = kv[0]*mw[hh][0] + kv[1]*mw[hh][1] + kv[2]*mw[hh][2] + kv[3]*mw[hh][3];
            #pragma unroll
            for (int off = 32; off >= 1; off >>= 1) {
                #pragma unroll
                for (int hh = 0; hh < HH; ++hh) sd[hh] += __shfl_xor(sd[hh], off, 64);
            }
            if (l == 0) {
                const int bb = row >> 11, a = row & (AA - 1);
                #pragma unroll
                for (int hh = 0; hh < HH; ++hh) {
                    float ax = fabsf(sd[hh]);
                    massT[((size_t)bb * HH + hh) * AA + a] =
                        (ax + log1pf(__expf(-2.0f * ax)) - 0.693147180559945f) * LOG2E;
                }
            }
        }
    }
}

// out[m][n] = sum_k Obuf[m][k] * W[n][k]
__global__ __launch_bounds__(256) void out_gemm(
    const bf16_t* __restrict__ Aop, const float* __restrict__ Bop,
    float* __restrict__ Cout)
{
    __shared__ __align__(16) bf16_t sA[64][72];
    __shared__ __align__(16) bf16_t sB[64][72];
    const int t = threadIdx.x;
    const int w = t >> 6, l = t & 63, g = l >> 4, q = l & 15;
    const int wm = w >> 1, wn = w & 1;
    const int m0 = blockIdx.x * 64, n0 = blockIdx.y * 64;
    const int r = t >> 2, s = t & 3;

    f32x4 acc[2][2] = {};

    for (int kt = 0; kt < 4; ++kt) {
        {
            const bf16_t* ga = Aop + (size_t)(m0 + r) * EE + kt * 64 + s * 16;
            *(bf16x8*)&sA[r][s * 16]     = *(const bf16x8*)(ga);
            *(bf16x8*)&sA[r][s * 16 + 8] = *(const bf16x8*)(ga + 8);
        }
        {
            const float* gb = Bop + (size_t)(n0 + r) * EE + kt * 64 + s * 16;
            float tmp[16];
            *(f32x4*)&tmp[0]  = *(const f32x4*)(gb + 0);
            *(f32x4*)&tmp[4]  = *(const f32x4*)(gb + 4);
            *(f32x4*)&tmp[8]  = *(const f32x4*)(gb + 8);
            *(f32x4*)&tmp[12] = *(const f32x4*)(gb + 12);
            bf16x8 w0, w1;
            #pragma unroll
            for (int i = 0; i < 8; ++i) { w0[i] = (bf16_t)tmp[i]; w1[i] = (bf16_t)tmp[8 + i]; }
            *(bf16x8*)&sB[r][s * 16]     = w0;
            *(bf16x8*)&sB[r][s * 16 + 8] = w1;
        }
        __syncthreads();
        #pragma unroll
        for (int ks = 0; ks < 2; ++ks) {
            bf16x8 aA[2], aB[2];
            #pragma unroll
            for (int f = 0; f < 2; ++f) {
                aA[f] = *(const bf16x8*)&sA[wm * 32 + f * 16 + q][ks * 32 + g * 8];
                aB[f] = *(const bf16x8*)&sB[wn * 32 + f * 16 + q][ks * 32 + g * 8];
            }
            #pragma unroll
            for (int fm = 0; fm < 2; ++fm)
            #pragma unroll
            for (int fn = 0; fn < 2; ++fn)
                acc[fm][fn] = mfma16(aA[fm], aB[fn], acc[fm][fn]);
        }
        __syncthreads();
    }
    #pragma unroll
    for (int fm = 0; fm < 2; ++fm)
    #pragma unroll
    for (int fn = 0; fn < 2; ++fn)
    #pragma unroll
    for (int j = 0; j < 4; ++j) {
        const int m = m0 + wm * 32 + fm * 16 + g * 4 + j;
        const int n = n0 + wn * 32 + fn * 16 + q;
        Cout[(size_t)m * EE + n] = acc[fm][fn][j];
    }
}

// ---------------- fused flash attention, static-max softmax ----------------
// Grid (32,4,4) x 512 threads = 8 waves: parity s = wv>>2 (a-tiles 2k+s),
// row-group rg = wv&3 (16 i-rows). Per-parity double-buffered K/V LDS via
// global_load_lds (pre-swizzled source, linear dest). Scores are provably
// bounded (|qk*scl| <~ 6, bias in [-4.3,0]) so softmax uses STATIC max 0:
// P = exp2(S) directly -- no running max, no cross-lane reduce, no rescale.
// Denominator via ones-column MFMA; epilogue combine is a pure add.
__global__ __launch_bounds__(512, 4) void attn_kernel(
    const bf16_t* __restrict__ Qp, const bf16_t* __restrict__ Kp,
    const bf16_t* __restrict__ Vt, const float* __restrict__ massT,
    const float* __restrict__ dist, bf16_t* __restrict__ Obuf)
{
    __shared__ __align__(16) bf16_t sK[2][2][4096];   // [parity][buf][64a x 64d] chunk^=(row&7)
    __shared__ __align__(16) bf16_t sV[2][2][4096];   // [parity][buf][64d x 64a'] chunk^=(row&7)
    __shared__ __align__(16) float  sM[2048];         // mass row (log2 domain)

    const int t = threadIdx.x;
    const int wv = t >> 6, l = t & 63, g = l >> 4, q = l & 15;
    const int s = wv >> 2, rg = wv & 3;
    const int h = blockIdx.y, b = blockIdx.z;
    const int i0 = blockIdx.x * 64;

    *(f32x4*)&sM[t * 4] = *(const f32x4*)(massT + ((size_t)b * HH + h) * AA + t * 4);

    // Q fragments (pre-scaled by SCL at projection)
    bf16x8 qf[2];
    #pragma unroll
    for (int ks = 0; ks < 2; ++ks)
        qf[ks] = *(const bf16x8*)(Qp + (size_t)(b * II + i0 + rg * 16 + q) * EE
                                     + h * 64 + ks * 32 + g * 8);

    // staging geometry: wave rg writes rows [rg*16, rg*16+16), lane covers (row, chunk)
    const int u0 = rg * 2;
    const int drow0 = u0 * 8 + (l >> 3);
    const int cs = (l & 7) ^ (drow0 & 7);   // constant pre-swizzled source chunk

    // incremental global pointers (parity stream starts at a0 = s*64)
    const bf16_t* pkg = Kp + ((size_t)b * AA + s * 64 + drow0) * EE + h * 64 + cs * 8;
    const bf16_t* pvg = Vt + (size_t)b * (AA * EE) + (size_t)s * (EE * 64)
                           + (size_t)(h * 64 + drow0) * 64 + cs * 8;
    const float*  pdg = dist + ((size_t)b * II + i0 + rg * 16 + q) * AA + s * 64 + g * 4;

    auto stage = [&](int kb) {
        #pragma unroll
        for (int u = 0; u < 2; ++u) {
            glds16(pkg + u * (8 * EE), &sK[s][kb][(u0 + u) * 512]);
            glds16(pvg + u * (8 * 64), &sV[s][kb][(u0 + u) * 512]);
        }
    };

    // dist double-set (indices compile-time after unroll 2)
    f32x4 rd[2][4];

    stage(0);
    pkg += 128 * EE; pvg += 2 * (EE * 64);
    #pragma unroll
    for (int fa = 0; fa < 4; ++fa) rd[0][fa] = *(const f32x4*)(pdg + fa * 16);
    pdg += 128;
    __syncthreads();

    f32x4 oacc[4] = {};
    f32x4 lacc = {};
    bf16x8 vone;
    #pragma unroll
    for (int j = 0; j < 8; ++j) vone[j] = (bf16_t)1.0f;

    int ma = s * 64;    // sM element offset for this tile

    #pragma unroll 2
    for (int k = 0; k < 16; ++k) {
        const int kb = k & 1;
        if (k < 15) {
            stage(kb ^ 1);
            pkg += 128 * EE; pvg += 2 * (EE * 64);
            #pragma unroll
            for (int fa = 0; fa < 4; ++fa)
                rd[(k + 1) & 1][fa] = *(const f32x4*)(pdg + fa * 16);
            pdg += 128;
        }

        // ---- QK^T: S^T[a = fa*16+4g+j][i = q] ----
        f32x4 st[4] = {};
        __builtin_amdgcn_s_setprio(1);
        #pragma unroll
        for (int fa = 0; fa < 4; ++fa) {
            const int row = fa * 16 + q;
            #pragma unroll
            for (int ks = 0; ks < 2; ++ks) {
                bf16x8 ak = *(const bf16x8*)&sK[s][kb][row * 64 + (((ks * 4 + g) ^ (row & 7)) * 8)];
                st[fa] = mfma16(ak, qf[ks], st[fa]);
            }
        }
        __builtin_amdgcn_s_setprio(0);

        // ---- P = exp2(qk*scl - mass*dist)  (static max: scores bounded) ----
        #pragma unroll
        for (int fa = 0; fa < 4; ++fa) {
            f32x4 ms = *(const f32x4*)&sM[ma + fa * 16 + g * 4];
            #pragma unroll
            for (int j = 0; j < 4; ++j)
                st[fa][j] = exp2f(fmaf(-ms[j], rd[kb][fa][j], st[fa][j]));
        }
        ma += 128;

        // ---- pack P: slot (g,j) -> a = ka*32 + 16*(j>>2) + 4g + (j&3) ----
        bf16x8 pa[2];
        #pragma unroll
        for (int ka = 0; ka < 2; ++ka)
        #pragma unroll
        for (int j = 0; j < 8; ++j)
            pa[ka][j] = (bf16_t)st[2 * ka + (j >> 2)][j & 3];

        // ---- PV + ones-column denominator ----
        __builtin_amdgcn_s_setprio(1);
        #pragma unroll
        for (int ka = 0; ka < 2; ++ka) {
            #pragma unroll
            for (int fd = 0; fd < 4; ++fd) {
                const int row = fd * 16 + q;
                bf16x8 bv = *(const bf16x8*)&sV[s][kb][row * 64 + (((ka * 4 + g) ^ (row & 7)) * 8)];
                oacc[fd] = mfma16(pa[ka], bv, oacc[fd]);
            }
            lacc = mfma16(pa[ka], vone, lacc);
        }
        __builtin_amdgcn_s_setprio(0);

        __syncthreads();
    }

    // ---- parity combine: pure add (no max merge) ----
    // slot: 21 floats: [0..3]=lacc, [4..19]=oacc
    float* cb = (float*)&sK[0][0][0];
    if (s == 1) {
        float* p = cb + (rg * 64 + l) * 21;
        *(f32x4*)(p) = lacc;
        #pragma unroll
        for (int fd = 0; fd < 4; ++fd) *(f32x4*)(p + 4 + fd * 4) = oacc[fd];
    }
    __syncthreads();
    if (s == 0) {
        const float* p = cb + (rg * 64 + l) * 21;
        const f32x4 lB = *(const f32x4*)(p);
        f32x4 inv;
        #pragma unroll
        for (int j = 0; j < 4; ++j) inv[j] = 1.0f / (lacc[j] + lB[j]);
        #pragma unroll
        for (int fd = 0; fd < 4; ++fd) {
            const f32x4 ob = *(const f32x4*)(p + 4 + fd * 4);
            #pragma unroll
            for (int j = 0; j < 4; ++j) {
                const float o = (oacc[fd][j] + ob[j]) * inv[j];
                Obuf[(size_t)(b * II + i0 + rg * 16 + g * 4 + j) * EE
                     + h * 64 + fd * 16 + q] = (bf16_t)o;
            }
        }
    }
}

extern "C" void kernel_launch(void* const* d_in, const int* in_sizes, int n_in,
                              void* d_out, int out_size, void* d_ws, size_t ws_size,
                              hipStream_t stream)
{
    const float* query  = (const float*)d_in[0];
    const float* key    = (const float*)d_in[1];
    const float* value  = (const float*)d_in[2];
    const float* dist   = (const float*)d_in[3];
    const float* in_w   = (const float*)d_in[4];
    const float* out_w  = (const float*)d_in[5];
    const float* mass_w = (const float*)d_in[6];
    float* out = (float*)d_out;

    char* ws = (char*)d_ws;
    bf16_t* Qp    = (bf16_t*)(ws);
    bf16_t* Kp    = (bf16_t*)(ws + 1 * 4194304);
    bf16_t* Vt    = (bf16_t*)(ws + 2 * 4194304);
    bf16_t* Obuf  = (bf16_t*)(ws + 3 * 4194304);
    float*  massT = (float*) (ws + 4 * 4194304);

    fused_pre<<<dim3(128, 4, 4), dim3(256), 0, stream>>>(
        query, key, value, in_w, mass_w, Qp, Kp, Vt, massT);
    attn_kernel<<<dim3(32, 4, 4), dim3(512), 0, stream>>>(Qp, Kp, Vt, massT, dist, Obuf);
    out_gemm<<<dim3(128, 4), dim3(256), 0, stream>>>(Obuf, out_w, out);
}